// Round 11
// baseline (135.185 us; speedup 1.0000x reference)
//
#include <hip/hip_runtime.h>

typedef __bf16 bf16_t;
typedef __bf16 bf16x4_t __attribute__((ext_vector_type(4)));
typedef __bf16 bf16x8 __attribute__((ext_vector_type(8)));
typedef float f32x4 __attribute__((ext_vector_type(4)));

#define NH 8
#define DH 32
#define QL 256
#define KL 256
#define CIN 64
#define HD 256  // NH*DH

__device__ __forceinline__ bf16_t f2bf(float x) { return (bf16_t)x; }

__device__ __forceinline__ f32x4 mfma16(bf16x8 a, bf16x8 b, f32x4 c) {
    return __builtin_amdgcn_mfma_f32_16x16x32_bf16(a, b, c, 0, 0, 0);
}

// raw v_exp_f32: D = 2^S0
__device__ __forceinline__ float exp2_raw(float x) {
    float r;
    asm("v_exp_f32 %0, %1" : "=v"(r) : "v"(x));
    return r;
}

// ---------------------------------------------------------------------------
// pack_w: one-time repack of Wq/Wk/Wv/Wo into fragment-native bf16 layout.
// Frag elem j at lane(quad,l16):
//   WqF/WkF/WvF: W[ks*32+quad*8+j][h*32 + nt*16 + l16]          (B-op, proj)
//   WoF (delta-packed): Wo[h*32 + (j>>2)*16 + quad*4 + (j&3)][nt*16+l16]
//     -- outproj k-sum relabeled so the O A-frag is lane-local (no bounce).
__launch_bounds__(256)
__global__ void pack_w(const float* __restrict__ Wq, const float* __restrict__ Wk,
                       const float* __restrict__ Wv, const float* __restrict__ Wo,
                       bf16_t* __restrict__ WqF, bf16_t* __restrict__ WkF,
                       bf16_t* __restrict__ WvF, bf16_t* __restrict__ WoF) {
    const int h = blockIdx.x;
    const int tid = threadIdx.x, lane = tid & 63, w = tid >> 6;
    const int quad = lane >> 4, l16 = lane & 15;
    if (w < 3) {
        const float* __restrict__ W = (w == 0) ? Wq : (w == 1 ? Wk : Wv);
        bf16_t* __restrict__ F = (w == 0) ? WqF : (w == 1 ? WkF : WvF);
#pragma unroll
        for (int nt = 0; nt < 2; ++nt)
#pragma unroll
            for (int ks = 0; ks < 2; ++ks) {
                bf16x8 f;
#pragma unroll
                for (int j = 0; j < 8; ++j)
                    f[j] = f2bf(W[(ks * 32 + quad * 8 + j) * HD + h * DH + nt * 16 + l16]);
                *(bf16x8*)&F[(size_t)((h * 4 + nt * 2 + ks) * 512) + lane * 8] = f;
            }
    } else {
#pragma unroll
        for (int nt = 0; nt < 4; ++nt) {
            bf16x8 f;
#pragma unroll
            for (int j = 0; j < 8; ++j)
                f[j] = f2bf(Wo[(h * DH + (j >> 2) * 16 + quad * 4 + (j & 3)) * CIN +
                               nt * 16 + l16]);
            *(bf16x8*)&WoF[(size_t)((h * 4 + nt) * 512) + lane * 8] = f;
        }
    }
}

// ---------------------------------------------------------------------------
// fused_pipe5: r10 + the QK k-axis relabeled by the fixed permutation
//   pi(q*8+j) = 16*(j>>2) + 4*q + (j&3)   (bijective; cancels between A & B)
// which buys, with ZERO xor-swizzles (padding only):
//  (1) swapped K-proj mfma(bk, xk): lane holds K[kv][nt*16+quad*4+r], r
//      contiguous -> K staging = 8 b64 stores/head/wave (was 32 scalar b16,
//      the dominant share of 4.78M conflict-cycles) into padded sK[256][40]
//      at col quad*8+nt*4; QK reads ONE aligned b128 at [row][quad*8]
//      (= the pi-packed chunk; read banks at the b128 floor).
//  (2) swapped Q-proj: qfr lane-local (qfr[j] = qc[j>>2][j&3]) -> the last
//      same-wave LDS round-trip (Q bounce) deleted; sPT removed (-9 KB).
// Everything else r10-verbatim: sVT/PV sigma-trick, delta-outproj, bias
// interleaved into PV, exp2-domain softmax, dbuf, 1 barrier/head.
__launch_bounds__(256, 2)
__global__ void fused_pipe5(const float* __restrict__ Xq, const float* __restrict__ Xkv,
                            const float* __restrict__ Mask, const float* __restrict__ Bias,
                            const bf16_t* __restrict__ WqF, const bf16_t* __restrict__ WkF,
                            const bf16_t* __restrict__ WvF, const bf16_t* __restrict__ WoF,
                            const float* __restrict__ Bo, float* __restrict__ Out) {
    const int b = blockIdx.x;
    const int s = b & 127, qq = b >> 7;   // s fastest: same-s blocks share an XCD
    const int tid = threadIdx.x, lane = tid & 63, w = tid >> 6;
    const int quad = lane >> 4, l16 = lane & 15;
    const int tg = qq * 4 + w;            // this wave's global q-tile (16 rows)
    const f32x4 vzero = {0.f, 0.f, 0.f, 0.f};
    constexpr float L2E = 1.4426950408889634f;

    __shared__ __attribute__((aligned(16))) bf16_t sK[2][KL * 40];   // 40 KB dbuf, padded
    __shared__ __attribute__((aligned(16))) bf16_t sVT[2][DH][264];  // 33 KB dbuf
    __shared__ __attribute__((aligned(16))) float sMask[KL];         //  1 KB

    // mask pre-combined AND pre-scaled by log2e: (m-1)*1e9*L2E
    if (tid < 64) {
        const f32x4 m4 = *(const f32x4*)&Mask[s * KL + tid * 4];
        f32x4 mm;
#pragma unroll
        for (int j = 0; j < 4; ++j) mm[j] = (m4[j] - 1.0f) * (1.0e9f * L2E);
        *(f32x4*)&sMask[tid * 4] = mm;
    }

    // ---- X fragments, register-resident for all 8 heads ----
    bf16x8 xk[4][2];  // Xkv A/B-frags: wave owns kv-tiles {4w..4w+3}
#pragma unroll
    for (int t = 0; t < 4; ++t) {
        const int row = (w * 4 + t) * 16 + l16;
        const float* src = &Xkv[(size_t)(s * QL + row) * CIN];
#pragma unroll
        for (int ks = 0; ks < 2; ++ks) {
            const f32x4 lo = *(const f32x4*)&src[ks * 32 + quad * 8];
            const f32x4 hi = *(const f32x4*)&src[ks * 32 + quad * 8 + 4];
            bf16x8 f;
#pragma unroll
            for (int j = 0; j < 4; ++j) { f[j] = f2bf(lo[j]); f[4 + j] = f2bf(hi[j]); }
            xk[t][ks] = f;
        }
    }
    bf16x8 xq[2];  // Xq frags, pre-scaled by (1/sqrt(32))*log2(e)
    {
        const int row = tg * 16 + l16;
        const float* src = &Xq[(size_t)(s * QL + row) * CIN];
        const float qs = 0.17677669529663687f * L2E;
#pragma unroll
        for (int ks = 0; ks < 2; ++ks) {
            const f32x4 lo = *(const f32x4*)&src[ks * 32 + quad * 8];
            const f32x4 hi = *(const f32x4*)&src[ks * 32 + quad * 8 + 4];
            bf16x8 f;
#pragma unroll
            for (int j = 0; j < 4; ++j) {
                f[j] = f2bf(lo[j] * qs);
                f[4 + j] = f2bf(hi[j] * qs);
            }
            xq[ks] = f;
        }
    }

    // K/V projection of head h into LDS buffer buf.
    // K swapped: mfma(bk, xk) -> lane holds K[kv=t16+l16][nt*16+quad*4+r];
    // b64 store to pi-packed sK[row][quad*8+nt*4..+3] (aligned 8B).
    // V unchanged (r10-verbatim).
    auto projKV = [&](int h, int buf) {
        bf16x8 bk[2][2], bv[2][2];
#pragma unroll
        for (int nt = 0; nt < 2; ++nt)
#pragma unroll
            for (int ks = 0; ks < 2; ++ks) {
                bk[nt][ks] = *(const bf16x8*)&WkF[(size_t)((h * 4 + nt * 2 + ks) * 512) + lane * 8];
                bv[nt][ks] = *(const bf16x8*)&WvF[(size_t)((h * 4 + nt * 2 + ks) * 512) + lane * 8];
            }
#pragma unroll
        for (int t = 0; t < 4; ++t) {
            const int row = (w * 4 + t) * 16 + l16;
#pragma unroll
            for (int nt = 0; nt < 2; ++nt) {
                f32x4 c = mfma16(bk[nt][0], xk[t][0], vzero);
                c = mfma16(bk[nt][1], xk[t][1], c);
                bf16x4_t p4;
#pragma unroll
                for (int r = 0; r < 4; ++r) p4[r] = f2bf(c[r]);
                *(bf16x4_t*)&sK[buf][row * 40 + quad * 8 + nt * 4] = p4;
            }
        }
#pragma unroll
        for (int t = 0; t < 4; ++t) {
            const int c0 = (w * 4 + t) * 16 + quad * 4;
#pragma unroll
            for (int nt = 0; nt < 2; ++nt) {
                f32x4 c = mfma16(xk[t][0], bv[nt][0], vzero);
                c = mfma16(xk[t][1], bv[nt][1], c);
                bf16x4_t p4;
#pragma unroll
                for (int r = 0; r < 4; ++r) p4[r] = f2bf(c[r]);
                *(bf16x4_t*)&sVT[buf][nt * 16 + l16][c0] = p4;
            }
        }
    };
    // Q projection, swapped & register-only: qfr[j] = Q[tg16+l16][pi(quad*8+j)]
    auto projQ = [&](int h) -> bf16x8 {
        bf16x8 bq[2][2];
#pragma unroll
        for (int nt = 0; nt < 2; ++nt)
#pragma unroll
            for (int ks = 0; ks < 2; ++ks)
                bq[nt][ks] = *(const bf16x8*)&WqF[(size_t)((h * 4 + nt * 2 + ks) * 512) + lane * 8];
        bf16x8 q;
#pragma unroll
        for (int nt = 0; nt < 2; ++nt) {
            f32x4 c = mfma16(bq[nt][0], xq[0], vzero);
            c = mfma16(bq[nt][1], xq[1], c);
#pragma unroll
            for (int r = 0; r < 4; ++r) q[nt * 4 + r] = f2bf(c[r]);
        }
        return q;
    };

    // va pair for PV chunk c (sigma layout; from the proven sVT tiles)
    auto loadVA = [&](int p, int c, bf16x8& v0, bf16x8& v1) {
        const bf16x4_t a00 = *(const bf16x4_t*)&sVT[p][l16][c * 32 + quad * 4];
        const bf16x4_t a01 = *(const bf16x4_t*)&sVT[p][l16][c * 32 + 16 + quad * 4];
        const bf16x4_t a10 = *(const bf16x4_t*)&sVT[p][16 + l16][c * 32 + quad * 4];
        const bf16x4_t a11 = *(const bf16x4_t*)&sVT[p][16 + l16][c * 32 + 16 + quad * 4];
#pragma unroll
        for (int j = 0; j < 4; ++j) {
            v0[j] = a00[j];
            v0[4 + j] = a01[j];
            v1[j] = a10[j];
            v1[4 + j] = a11[j];
        }
    };

    f32x4 acc[4];  // output accumulator: 16 q-rows x 64 out-cols
#pragma unroll
    for (int nt = 0; nt < 4; ++nt) acc[nt] = vzero;

    // ---- prologue: bias(0) in flight, K/V(0) -> buf0, qfr(0) ready ----
    f32x4 sv[16];
    {
        const float* bb = &Bias[(size_t)(tg * 16 + l16) * KL];
#pragma unroll
        for (int ct = 0; ct < 16; ++ct) sv[ct] = *(const f32x4*)&bb[ct * 16 + quad * 4];
    }
    projKV(0, 0);
    bf16x8 qfr = projQ(0);
    __syncthreads();  // buf0 + sMask visible
#pragma unroll
    for (int ct = 0; ct < 16; ++ct) {
        const f32x4 m4 = *(const f32x4*)&sMask[ct * 16 + quad * 4];
#pragma unroll
        for (int r = 0; r < 4; ++r) sv[ct][r] = sv[ct][r] * L2E + m4[r];
    }

#pragma unroll 1
    for (int h = 0; h < NH; ++h) {
        const int p = h & 1;
        const int hn = (h + 1) & 7;  // branchless bias prefetch head (h=7 -> dummy)
        const float* bbn = &Bias[(size_t)(hn * QL + tg * 16 + l16) * KL];

        // ---- QK immediately: one aligned b128 per kv-tile (pi-packed) ----
#pragma unroll
        for (int ct = 0; ct < 16; ++ct) {
            const bf16x8 ak = *(const bf16x8*)&sK[p][(ct * 16 + l16) * 40 + quad * 8];
            sv[ct] = mfma16(ak, qfr, sv[ct]);  // S' = S*log2e, bias+mask in C
        }

        // ---- proj(h+1) into buf 1-p: independent MFMA filler ----
        if (h + 1 < NH) projKV(h + 1, p ^ 1);

        // ---- Wo frags (delta-packed; global, L2-hot; used at phase end) ----
        bf16x8 bwo[4];
#pragma unroll
        for (int nt = 0; nt < 4; ++nt)
            bwo[nt] = *(const bf16x8*)&WoF[(size_t)((h * 4 + nt) * 512) + lane * 8];

        // ---- va(0) prefetch: sVT[p] valid since the phase barrier ----
        bf16x8 vc0, vc1;
        loadVA(p, 0, vc0, vc1);

        // ---- softmax in exp2 domain (tree-reduced max; raw v_exp_f32) ----
        f32x4 vmx = sv[0];
#pragma unroll
        for (int ct = 1; ct < 16; ++ct)
#pragma unroll
            for (int r = 0; r < 4; ++r) vmx[r] = fmaxf(vmx[r], sv[ct][r]);
        float mx = fmaxf(fmaxf(vmx[0], vmx[1]), fmaxf(vmx[2], vmx[3]));
        mx = fmaxf(mx, __shfl_xor(mx, 16, 64));
        mx = fmaxf(mx, __shfl_xor(mx, 32, 64));
        f32x4 vsum = vzero;
#pragma unroll
        for (int ct = 0; ct < 16; ++ct)
#pragma unroll
            for (int r = 0; r < 4; ++r) {
                const float e = exp2_raw(sv[ct][r] - mx);
                sv[ct][r] = e;
                vsum[r] += e;
            }
        float sum = (vsum[0] + vsum[1]) + (vsum[2] + vsum[3]);
        sum += __shfl_xor(sum, 16, 64);
        sum += __shfl_xor(sum, 32, 64);
        const float rs = 1.0f / sum;  // consumed only after PV -> hides under it

        // ---- swapped PV (LDS-free P), va pipelined, bias loads interleaved ----
        f32x4 ot0 = vzero, ot1 = vzero;
#pragma unroll
        for (int c = 0; c < 8; ++c) {
            bf16x8 vn0, vn1;
            if (c < 7) loadVA(p, c + 1, vn0, vn1);
            bf16x8 pf;
#pragma unroll
            for (int j = 0; j < 4; ++j) {
                pf[j] = f2bf(sv[2 * c][j]);
                pf[4 + j] = f2bf(sv[2 * c + 1][j]);
            }
            // sv[2c],[2c+1] dead now -> refill with bias(h+1): max load-to-use
            sv[2 * c] = *(const f32x4*)&bbn[(2 * c) * 16 + quad * 4];
            sv[2 * c + 1] = *(const f32x4*)&bbn[(2 * c + 1) * 16 + quad * 4];
            ot0 = mfma16(vc0, pf, ot0);  // O^T[d=quad*4+r][q=l16], d-tile 0
            ot1 = mfma16(vc1, pf, ot1);  // d-tile 1
            vc0 = vn0;
            vc1 = vn1;
        }

        // ---- outproj, LDS-free O: af[j] = ot[j>>2][j&3]*rs (delta-packed Wo) ----
        {
            bf16x8 af;
#pragma unroll
            for (int r = 0; r < 4; ++r) {
                af[r] = f2bf(ot0[r] * rs);
                af[4 + r] = f2bf(ot1[r] * rs);
            }
#pragma unroll
            for (int nt = 0; nt < 4; ++nt) acc[nt] = mfma16(af, bwo[nt], acc[nt]);
        }

        // ---- tail: Q(h+1) register-only; fold mask into resident bias ----
        if (h + 1 < NH) {
            qfr = projQ(h + 1);
#pragma unroll
            for (int ct = 0; ct < 16; ++ct) {
                const f32x4 m4 = *(const f32x4*)&sMask[ct * 16 + quad * 4];
#pragma unroll
                for (int r = 0; r < 4; ++r) sv[ct][r] = sv[ct][r] * L2E + m4[r];
            }
        }

        __syncthreads();  // single barrier/head: buf 1-p ready, buf p free
    }

    // -------------------- epilogue: direct store --------------------
    const int orow = s * QL + tg * 16 + quad * 4;
#pragma unroll
    for (int nt = 0; nt < 4; ++nt) {
        const float bo = Bo[nt * 16 + l16];
#pragma unroll
        for (int r = 0; r < 4; ++r)
            Out[(size_t)(orow + r) * CIN + nt * 16 + l16] = acc[nt][r] + bo;
    }
}

extern "C" void kernel_launch(void* const* d_in, const int* in_sizes, int n_in,
                              void* d_out, int out_size, void* d_ws, size_t ws_size,
                              hipStream_t stream) {
    const float* Xq   = (const float*)d_in[0];
    const float* Xkv  = (const float*)d_in[1];
    const float* Mask = (const float*)d_in[2];
    const float* Bias = (const float*)d_in[3];
    const float* Wq   = (const float*)d_in[4];
    const float* Wk   = (const float*)d_in[5];
    const float* Wv   = (const float*)d_in[6];
    const float* Wo   = (const float*)d_in[7];
    const float* Bo   = (const float*)d_in[8];
    float* Out = (float*)d_out;

    // 128 KB of fragment-native weights at the head of ws
    bf16_t* WqF = (bf16_t*)d_ws;
    bf16_t* WkF = WqF + 16384;
    bf16_t* WvF = WkF + 16384;
    bf16_t* WoF = WvF + 16384;

    pack_w<<<dim3(NH), 256, 0, stream>>>(Wq, Wk, Wv, Wo, WqF, WkF, WvF, WoF);
    fused_pipe5<<<dim3(512), 256, 0, stream>>>(Xq, Xkv, Mask, Bias,
                                               WqF, WkF, WvF, WoF, Bo, Out);
}